// Round 2
// baseline (5697.603 us; speedup 1.0000x reference)
//
#include <hip/hip_runtime.h>
#include <hip/hip_bf16.h>

#define N_NODES 100000
#define N_HEDGES 20000
#define N_EDGES 800000

typedef __hip_bfloat16 bf16;

__device__ __forceinline__ float b2f(bf16 v) { return __bfloat162float(v); }
__device__ __forceinline__ bf16 f2b(float v) { return __float2bfloat16(v); }

// ---------------------------------------------------------------------------
// xl[t] = x @ W_conv[t]  (both types in one pass; W in LDS; x row broadcast
// via shuffles; lane j owns output column j). xl stored bf16 (ws economy).
// ---------------------------------------------------------------------------
__global__ __launch_bounds__(256) void k_conv(const float* __restrict__ x,
                                              const float* __restrict__ Wc,
                                              bf16* __restrict__ xl) {
    __shared__ float W[2 * 64 * 64];
    for (int i = threadIdx.x; i < 2 * 64 * 64; i += 256) W[i] = Wc[i];
    __syncthreads();
    int wid = threadIdx.x >> 6, lane = threadIdx.x & 63;
    for (int row = blockIdx.x * 4 + wid; row < N_NODES; row += gridDim.x * 4) {
        float xv = x[(size_t)row * 64 + lane];
        float a0 = 0.f, a1 = 0.f;
#pragma unroll
        for (int k = 0; k < 64; ++k) {
            float xb = __shfl(xv, k);
            a0 += xb * W[k * 64 + lane];
            a1 += xb * W[4096 + k * 64 + lane];
        }
        xl[(size_t)row * 64 + lane] = f2b(a0);
        xl[(size_t)N_NODES * 64 + (size_t)row * 64 + lane] = f2b(a1);
    }
}

// ---------------------------------------------------------------------------
// Degrees: D[t][node] += 1, B[t][hedge] += 1 per incidence
// ---------------------------------------------------------------------------
__global__ __launch_bounds__(256) void k_deg(const int* __restrict__ node_idx,
                                             const int* __restrict__ hedge_idx,
                                             const int* __restrict__ attr,
                                             float* __restrict__ Ddeg,
                                             float* __restrict__ Bdeg) {
    int e = blockIdx.x * 256 + threadIdx.x;
    if (e < N_EDGES) {
        int t = attr[e];
        atomicAdd(&Ddeg[t * N_NODES + node_idx[e]], 1.0f);
        atomicAdd(&Bdeg[t * N_HEDGES + hedge_idx[e]], 1.0f);
    }
}

// ---------------------------------------------------------------------------
// ef[t][h] += xl[t][node]  (wave per edge, lane = feature dim)
// ---------------------------------------------------------------------------
__global__ __launch_bounds__(256) void k_ef(const int* __restrict__ node_idx,
                                            const int* __restrict__ hedge_idx,
                                            const int* __restrict__ attr,
                                            const bf16* __restrict__ xl,
                                            float* __restrict__ ef) {
    int e = blockIdx.x * 4 + (threadIdx.x >> 6);
    int lane = threadIdx.x & 63;
    if (e < N_EDGES) {
        int t = attr[e], n = node_idx[e], h = hedge_idx[e];
        float v = b2f(xl[((size_t)t * N_NODES + n) * 64 + lane]);
        atomicAdd(&ef[((size_t)t * N_HEDGES + h) * 64 + lane], v);
    }
}

// ---------------------------------------------------------------------------
// ef *= Binv  (Binv = 1/B where B>0 else 0)
// ---------------------------------------------------------------------------
__global__ __launch_bounds__(256) void k_scale(float* __restrict__ ef,
                                               const float* __restrict__ Bdeg) {
    int i = blockIdx.x * 256 + threadIdx.x;
    if (i < 2 * N_HEDGES * 64) {
        float b = Bdeg[i >> 6];
        ef[i] = (b > 0.f) ? ef[i] * (1.0f / b) : 0.f;
    }
}

// ---------------------------------------------------------------------------
// no[t][node] += ef[t][h]  (wave per edge)
// ---------------------------------------------------------------------------
__global__ __launch_bounds__(256) void k_no(const int* __restrict__ node_idx,
                                            const int* __restrict__ hedge_idx,
                                            const int* __restrict__ attr,
                                            const float* __restrict__ ef,
                                            float* __restrict__ no) {
    int e = blockIdx.x * 4 + (threadIdx.x >> 6);
    int lane = threadIdx.x & 63;
    if (e < N_EDGES) {
        int t = attr[e], n = node_idx[e], h = hedge_idx[e];
        float v = ef[((size_t)t * N_HEDGES + h) * 64 + lane];
        atomicAdd(&no[((size_t)t * N_NODES + n) * 64 + lane], v);
    }
}

// ---------------------------------------------------------------------------
// h = relu( [no0*Dinv0 + bc0, no1*Dinv1 + bc1] @ W_mix + b_mix )
// ---------------------------------------------------------------------------
__global__ __launch_bounds__(256) void k_mix(const float* __restrict__ no,
                                             const float* __restrict__ Ddeg,
                                             const float* __restrict__ bconv,
                                             const float* __restrict__ Wm_g,
                                             const float* __restrict__ bm_g,
                                             float* __restrict__ hbuf) {
    __shared__ float Wm[128 * 64];
    __shared__ float bc[128];
    __shared__ float bm[64];
    for (int i = threadIdx.x; i < 128 * 64; i += 256) Wm[i] = Wm_g[i];
    if (threadIdx.x < 128) bc[threadIdx.x] = bconv[threadIdx.x];
    if (threadIdx.x < 64) bm[threadIdx.x] = bm_g[threadIdx.x];
    __syncthreads();
    int wid = threadIdx.x >> 6, lane = threadIdx.x & 63;
    for (int row = blockIdx.x * 4 + wid; row < N_NODES; row += gridDim.x * 4) {
        float d0 = Ddeg[row], d1 = Ddeg[N_NODES + row];
        float di0 = d0 > 0.f ? 1.0f / d0 : 0.f;
        float di1 = d1 > 0.f ? 1.0f / d1 : 0.f;
        float in0 = no[(size_t)row * 64 + lane] * di0 + bc[lane];
        float in1 = no[((size_t)N_NODES + row) * 64 + lane] * di1 + bc[64 + lane];
        float acc = bm[lane];
#pragma unroll
        for (int k = 0; k < 64; ++k) {
            acc += __shfl(in0, k) * Wm[k * 64 + lane];
            acc += __shfl(in1, k) * Wm[(64 + k) * 64 + lane];
        }
        hbuf[(size_t)row * 64 + lane] = fmaxf(acc, 0.f);
    }
}

// ---------------------------------------------------------------------------
// GRU cell + output projection (cols 0..2 only), torch gate order (r,z,n).
// ---------------------------------------------------------------------------
__global__ __launch_bounds__(1024) void k_gru(const float* __restrict__ hbuf,
                                              const float* __restrict__ h_prev,
                                              const float* __restrict__ Wih_g,
                                              const float* __restrict__ Whh_g,
                                              const float* __restrict__ bih_g,
                                              const float* __restrict__ bhh_g,
                                              const float* __restrict__ Wro_g,
                                              const float* __restrict__ bro_g,
                                              float* __restrict__ out_h,
                                              float* __restrict__ out_o) {
    __shared__ float Wih[64 * 192];
    __shared__ float Whh[64 * 192];
    __shared__ float bih[192], bhh[192];
    __shared__ float wro[64 * 3];
    __shared__ float bro[3];
    for (int i = threadIdx.x; i < 64 * 192; i += 1024) {
        Wih[i] = Wih_g[i];
        Whh[i] = Whh_g[i];
    }
    if (threadIdx.x < 192) {
        bih[threadIdx.x] = bih_g[threadIdx.x];
        bhh[threadIdx.x] = bhh_g[threadIdx.x];
    }
    if (threadIdx.x < 64 * 3) {
        int j = threadIdx.x / 3, c = threadIdx.x % 3;
        wro[threadIdx.x] = Wro_g[j * 64 + c];
    }
    if (threadIdx.x < 3) bro[threadIdx.x] = bro_g[threadIdx.x];
    __syncthreads();
    int wid = threadIdx.x >> 6, lane = threadIdx.x & 63;
    for (int row = blockIdx.x * 16 + wid; row < N_NODES; row += gridDim.x * 16) {
        float hv = hbuf[(size_t)row * 64 + lane];
        float pv = h_prev[(size_t)row * 64 + lane];
        float air = bih[lane], aiz = bih[64 + lane], ain = bih[128 + lane];
        float ahr = bhh[lane], ahz = bhh[64 + lane], ahn = bhh[128 + lane];
#pragma unroll
        for (int k = 0; k < 64; ++k) {
            float hb = __shfl(hv, k), pb = __shfl(pv, k);
            air += hb * Wih[k * 192 + lane];
            aiz += hb * Wih[k * 192 + 64 + lane];
            ain += hb * Wih[k * 192 + 128 + lane];
            ahr += pb * Whh[k * 192 + lane];
            ahz += pb * Whh[k * 192 + 64 + lane];
            ahn += pb * Whh[k * 192 + 128 + lane];
        }
        float r = 1.f / (1.f + expf(-(air + ahr)));
        float z = 1.f / (1.f + expf(-(aiz + ahz)));
        float nn = tanhf(ain + r * ahn);
        float hn = (1.f - z) * nn + z * pv;
        out_h[(size_t)row * 64 + lane] = hn;
        float p0 = hn * wro[lane * 3 + 0];
        float p1 = hn * wro[lane * 3 + 1];
        float p2 = hn * wro[lane * 3 + 2];
#pragma unroll
        for (int off = 32; off > 0; off >>= 1) {
            p0 += __shfl_down(p0, off);
            p1 += __shfl_down(p1, off);
            p2 += __shfl_down(p2, off);
        }
        if (lane == 0) {
            out_o[(size_t)row * 3 + 0] = p0 + bro[0];
            out_o[(size_t)row * 3 + 1] = p1 + bro[1];
            out_o[(size_t)row * 3 + 2] = p2 + bro[2];
        }
    }
}

extern "C" void kernel_launch(void* const* d_in, const int* in_sizes, int n_in,
                              void* d_out, int out_size, void* d_ws, size_t ws_size,
                              hipStream_t stream) {
    const float* x        = (const float*)d_in[0];
    const float* h_prev   = (const float*)d_in[1];
    const int* node_idx   = (const int*)d_in[2];
    const int* hedge_idx  = (const int*)d_in[3];
    const int* edge_attr  = (const int*)d_in[4];
    const float* W_conv   = (const float*)d_in[5];
    const float* b_conv   = (const float*)d_in[6];
    const float* W_mix    = (const float*)d_in[7];
    const float* b_mix    = (const float*)d_in[8];
    const float* W_ih     = (const float*)d_in[9];
    const float* W_hh     = (const float*)d_in[10];
    const float* b_ih     = (const float*)d_in[11];
    const float* b_hh     = (const float*)d_in[12];
    const float* W_ro     = (const float*)d_in[13];
    const float* b_ro     = (const float*)d_in[14];

    // Workspace layout (88 MB total):
    //   Ddeg [2][N] fp32 | Bdeg [2][H] fp32 | ef [2][H][64] fp32 |
    //   no [2][N][64] fp32 | xl [2][N][64] bf16  (hbuf [N][64] fp32 aliases xl
    //   after k_ef — xl is dead once k_ef completes; exact-fit 25.6 MB)
    char* ws    = (char*)d_ws;
    float* Ddeg = (float*)ws;
    float* Bdeg = Ddeg + 2 * N_NODES;
    float* ef   = Bdeg + 2 * N_HEDGES;
    float* no   = ef + (size_t)2 * N_HEDGES * 64;
    bf16* xl    = (bf16*)(no + (size_t)2 * N_NODES * 64);
    float* hbuf = (float*)xl;  // alias: valid after k_ef

    size_t zero_bytes = ((size_t)2 * N_NODES + 2 * N_HEDGES +
                         (size_t)2 * N_HEDGES * 64 + (size_t)2 * N_NODES * 64) *
                        sizeof(float);
    hipMemsetAsync(d_ws, 0, zero_bytes, stream);

    float* out_h = (float*)d_out;
    float* out_o = out_h + (size_t)N_NODES * 64;

    k_conv<<<2048, 256, 0, stream>>>(x, W_conv, xl);
    k_deg<<<(N_EDGES + 255) / 256, 256, 0, stream>>>(node_idx, hedge_idx, edge_attr, Ddeg, Bdeg);
    k_ef<<<N_EDGES / 4, 256, 0, stream>>>(node_idx, hedge_idx, edge_attr, xl, ef);
    k_scale<<<(2 * N_HEDGES * 64 + 255) / 256, 256, 0, stream>>>(ef, Bdeg);
    k_no<<<N_EDGES / 4, 256, 0, stream>>>(node_idx, hedge_idx, edge_attr, ef, no);
    k_mix<<<2048, 256, 0, stream>>>(no, Ddeg, b_conv, W_mix, b_mix, hbuf);
    k_gru<<<2048, 1024, 0, stream>>>(hbuf, h_prev, W_ih, W_hh, b_ih, b_hh, W_ro, b_ro, out_h, out_o);
}

// Round 3
// 1340.447 us; speedup vs baseline: 4.2505x; 4.2505x over previous
//
#include <hip/hip_runtime.h>
#include <hip/hip_bf16.h>

#define N_NODES 100000
#define N_HEDGES 20000
#define N_EDGES 800000

typedef __hip_bfloat16 bf16;

__device__ __forceinline__ float b2f(bf16 v) { return __bfloat162float(v); }
__device__ __forceinline__ bf16 f2b(float v) { return __float2bfloat16(v); }

// ---------------------------------------------------------------------------
// xl[t] = x @ W_conv[t]  (both types in one pass; W in LDS; x row broadcast
// via shuffles; lane j owns output column j). xl stored bf16 (ws economy).
// ---------------------------------------------------------------------------
__global__ __launch_bounds__(256) void k_conv(const float* __restrict__ x,
                                              const float* __restrict__ Wc,
                                              bf16* __restrict__ xl) {
    __shared__ float W[2 * 64 * 64];
    for (int i = threadIdx.x; i < 2 * 64 * 64; i += 256) W[i] = Wc[i];
    __syncthreads();
    int wid = threadIdx.x >> 6, lane = threadIdx.x & 63;
    for (int row = blockIdx.x * 4 + wid; row < N_NODES; row += gridDim.x * 4) {
        float xv = x[(size_t)row * 64 + lane];
        float a0 = 0.f, a1 = 0.f;
#pragma unroll 16
        for (int k = 0; k < 64; ++k) {
            float xb = __shfl(xv, k);
            a0 += xb * W[k * 64 + lane];
            a1 += xb * W[4096 + k * 64 + lane];
        }
        xl[(size_t)row * 64 + lane] = f2b(a0);
        xl[(size_t)N_NODES * 64 + (size_t)row * 64 + lane] = f2b(a1);
    }
}

// ---------------------------------------------------------------------------
// Degrees: D[t][node] += 1, B[t][hedge] += 1 per incidence
// ---------------------------------------------------------------------------
__global__ __launch_bounds__(256) void k_deg(const int* __restrict__ node_idx,
                                             const int* __restrict__ hedge_idx,
                                             const int* __restrict__ attr,
                                             float* __restrict__ Ddeg,
                                             float* __restrict__ Bdeg) {
    int e = blockIdx.x * 256 + threadIdx.x;
    if (e < N_EDGES) {
        int t = attr[e];
        atomicAdd(&Ddeg[t * N_NODES + node_idx[e]], 1.0f);
        atomicAdd(&Bdeg[t * N_HEDGES + hedge_idx[e]], 1.0f);
    }
}

// ---------------------------------------------------------------------------
// ef[t][h] += xl[t][node]  (wave per edge, lane = feature dim)
// ---------------------------------------------------------------------------
__global__ __launch_bounds__(256) void k_ef(const int* __restrict__ node_idx,
                                            const int* __restrict__ hedge_idx,
                                            const int* __restrict__ attr,
                                            const bf16* __restrict__ xl,
                                            float* __restrict__ ef) {
    int e = blockIdx.x * 4 + (threadIdx.x >> 6);
    int lane = threadIdx.x & 63;
    if (e < N_EDGES) {
        int t = attr[e], n = node_idx[e], h = hedge_idx[e];
        float v = b2f(xl[((size_t)t * N_NODES + n) * 64 + lane]);
        atomicAdd(&ef[((size_t)t * N_HEDGES + h) * 64 + lane], v);
    }
}

// ---------------------------------------------------------------------------
// ef *= Binv  (Binv = 1/B where B>0 else 0)
// ---------------------------------------------------------------------------
__global__ __launch_bounds__(256) void k_scale(float* __restrict__ ef,
                                               const float* __restrict__ Bdeg) {
    int i = blockIdx.x * 256 + threadIdx.x;
    if (i < 2 * N_HEDGES * 64) {
        float b = Bdeg[i >> 6];
        ef[i] = (b > 0.f) ? ef[i] * (1.0f / b) : 0.f;
    }
}

// ---------------------------------------------------------------------------
// no[t][node] += ef[t][h]  (wave per edge)
// ---------------------------------------------------------------------------
__global__ __launch_bounds__(256) void k_no(const int* __restrict__ node_idx,
                                            const int* __restrict__ hedge_idx,
                                            const int* __restrict__ attr,
                                            const float* __restrict__ ef,
                                            float* __restrict__ no) {
    int e = blockIdx.x * 4 + (threadIdx.x >> 6);
    int lane = threadIdx.x & 63;
    if (e < N_EDGES) {
        int t = attr[e], n = node_idx[e], h = hedge_idx[e];
        float v = ef[((size_t)t * N_HEDGES + h) * 64 + lane];
        atomicAdd(&no[((size_t)t * N_NODES + n) * 64 + lane], v);
    }
}

// ---------------------------------------------------------------------------
// h = relu( [no0*Dinv0 + bc0, no1*Dinv1 + bc1] @ W_mix + b_mix )
// ---------------------------------------------------------------------------
__global__ __launch_bounds__(256) void k_mix(const float* __restrict__ no,
                                             const float* __restrict__ Ddeg,
                                             const float* __restrict__ bconv,
                                             const float* __restrict__ Wm_g,
                                             const float* __restrict__ bm_g,
                                             float* __restrict__ hbuf) {
    __shared__ float Wm[128 * 64];
    __shared__ float bc[128];
    __shared__ float bm[64];
    for (int i = threadIdx.x; i < 128 * 64; i += 256) Wm[i] = Wm_g[i];
    if (threadIdx.x < 128) bc[threadIdx.x] = bconv[threadIdx.x];
    if (threadIdx.x < 64) bm[threadIdx.x] = bm_g[threadIdx.x];
    __syncthreads();
    int wid = threadIdx.x >> 6, lane = threadIdx.x & 63;
    for (int row = blockIdx.x * 4 + wid; row < N_NODES; row += gridDim.x * 4) {
        float d0 = Ddeg[row], d1 = Ddeg[N_NODES + row];
        float di0 = d0 > 0.f ? 1.0f / d0 : 0.f;
        float di1 = d1 > 0.f ? 1.0f / d1 : 0.f;
        float in0 = no[(size_t)row * 64 + lane] * di0 + bc[lane];
        float in1 = no[((size_t)N_NODES + row) * 64 + lane] * di1 + bc[64 + lane];
        float acc = bm[lane];
#pragma unroll 16
        for (int k = 0; k < 64; ++k) {
            acc += __shfl(in0, k) * Wm[k * 64 + lane];
            acc += __shfl(in1, k) * Wm[(64 + k) * 64 + lane];
        }
        hbuf[(size_t)row * 64 + lane] = fmaxf(acc, 0.f);
    }
}

// ---------------------------------------------------------------------------
// GRU cell + output projection (cols 0..2 only), torch gate order (r,z,n).
// block=256 + launch_bounds(256,2): 256-VGPR budget — the round-2 version
// capped VGPRs at 64 (block=1024) and spilled ~12 GB of scratch to HBM.
// Weights bf16 in LDS (51 KB) -> 3 blocks/CU instead of 1.
// ---------------------------------------------------------------------------
__global__ __launch_bounds__(256, 2) void k_gru(const float* __restrict__ hbuf,
                                                const float* __restrict__ h_prev,
                                                const float* __restrict__ Wih_g,
                                                const float* __restrict__ Whh_g,
                                                const float* __restrict__ bih_g,
                                                const float* __restrict__ bhh_g,
                                                const float* __restrict__ Wro_g,
                                                const float* __restrict__ bro_g,
                                                float* __restrict__ out_h,
                                                float* __restrict__ out_o) {
    __shared__ bf16 Wih[64 * 192];
    __shared__ bf16 Whh[64 * 192];
    __shared__ float bih[192], bhh[192];
    __shared__ float wro[64 * 3];
    __shared__ float bro[3];
    for (int i = threadIdx.x; i < 64 * 192; i += 256) {
        Wih[i] = f2b(Wih_g[i]);
        Whh[i] = f2b(Whh_g[i]);
    }
    if (threadIdx.x < 192) {
        bih[threadIdx.x] = bih_g[threadIdx.x];
        bhh[threadIdx.x] = bhh_g[threadIdx.x];
    }
    if (threadIdx.x < 64 * 3) {
        int j = threadIdx.x / 3, c = threadIdx.x % 3;
        wro[threadIdx.x] = Wro_g[j * 64 + c];
    }
    if (threadIdx.x < 3) bro[threadIdx.x] = bro_g[threadIdx.x];
    __syncthreads();
    int wid = threadIdx.x >> 6, lane = threadIdx.x & 63;
    for (int row = blockIdx.x * 4 + wid; row < N_NODES; row += gridDim.x * 4) {
        float hv = hbuf[(size_t)row * 64 + lane];
        float pv = h_prev[(size_t)row * 64 + lane];
        float air = bih[lane], aiz = bih[64 + lane], ain = bih[128 + lane];
        float ahr = bhh[lane], ahz = bhh[64 + lane], ahn = bhh[128 + lane];
#pragma unroll 16
        for (int k = 0; k < 64; ++k) {
            float hb = __shfl(hv, k), pb = __shfl(pv, k);
            air += hb * b2f(Wih[k * 192 + lane]);
            aiz += hb * b2f(Wih[k * 192 + 64 + lane]);
            ain += hb * b2f(Wih[k * 192 + 128 + lane]);
            ahr += pb * b2f(Whh[k * 192 + lane]);
            ahz += pb * b2f(Whh[k * 192 + 64 + lane]);
            ahn += pb * b2f(Whh[k * 192 + 128 + lane]);
        }
        float r = 1.f / (1.f + expf(-(air + ahr)));
        float z = 1.f / (1.f + expf(-(aiz + ahz)));
        float nn = tanhf(ain + r * ahn);
        float hn = (1.f - z) * nn + z * pv;
        out_h[(size_t)row * 64 + lane] = hn;
        float p0 = hn * wro[lane * 3 + 0];
        float p1 = hn * wro[lane * 3 + 1];
        float p2 = hn * wro[lane * 3 + 2];
#pragma unroll
        for (int off = 32; off > 0; off >>= 1) {
            p0 += __shfl_down(p0, off);
            p1 += __shfl_down(p1, off);
            p2 += __shfl_down(p2, off);
        }
        if (lane == 0) {
            out_o[(size_t)row * 3 + 0] = p0 + bro[0];
            out_o[(size_t)row * 3 + 1] = p1 + bro[1];
            out_o[(size_t)row * 3 + 2] = p2 + bro[2];
        }
    }
}

extern "C" void kernel_launch(void* const* d_in, const int* in_sizes, int n_in,
                              void* d_out, int out_size, void* d_ws, size_t ws_size,
                              hipStream_t stream) {
    const float* x        = (const float*)d_in[0];
    const float* h_prev   = (const float*)d_in[1];
    const int* node_idx   = (const int*)d_in[2];
    const int* hedge_idx  = (const int*)d_in[3];
    const int* edge_attr  = (const int*)d_in[4];
    const float* W_conv   = (const float*)d_in[5];
    const float* b_conv   = (const float*)d_in[6];
    const float* W_mix    = (const float*)d_in[7];
    const float* b_mix    = (const float*)d_in[8];
    const float* W_ih     = (const float*)d_in[9];
    const float* W_hh     = (const float*)d_in[10];
    const float* b_ih     = (const float*)d_in[11];
    const float* b_hh     = (const float*)d_in[12];
    const float* W_ro     = (const float*)d_in[13];
    const float* b_ro     = (const float*)d_in[14];

    // Workspace layout (88 MB total):
    //   Ddeg [2][N] fp32 | Bdeg [2][H] fp32 | ef [2][H][64] fp32 |
    //   no [2][N][64] fp32 | xl [2][N][64] bf16  (hbuf [N][64] fp32 aliases xl
    //   after k_ef — xl is dead once k_ef completes; exact-fit 25.6 MB)
    char* ws    = (char*)d_ws;
    float* Ddeg = (float*)ws;
    float* Bdeg = Ddeg + 2 * N_NODES;
    float* ef   = Bdeg + 2 * N_HEDGES;
    float* no   = ef + (size_t)2 * N_HEDGES * 64;
    bf16* xl    = (bf16*)(no + (size_t)2 * N_NODES * 64);
    float* hbuf = (float*)xl;  // alias: valid after k_ef

    size_t zero_bytes = ((size_t)2 * N_NODES + 2 * N_HEDGES +
                         (size_t)2 * N_HEDGES * 64 + (size_t)2 * N_NODES * 64) *
                        sizeof(float);
    hipMemsetAsync(d_ws, 0, zero_bytes, stream);

    float* out_h = (float*)d_out;
    float* out_o = out_h + (size_t)N_NODES * 64;

    k_conv<<<2048, 256, 0, stream>>>(x, W_conv, xl);
    k_deg<<<(N_EDGES + 255) / 256, 256, 0, stream>>>(node_idx, hedge_idx, edge_attr, Ddeg, Bdeg);
    k_ef<<<N_EDGES / 4, 256, 0, stream>>>(node_idx, hedge_idx, edge_attr, xl, ef);
    k_scale<<<(2 * N_HEDGES * 64 + 255) / 256, 256, 0, stream>>>(ef, Bdeg);
    k_no<<<N_EDGES / 4, 256, 0, stream>>>(node_idx, hedge_idx, edge_attr, ef, no);
    k_mix<<<2048, 256, 0, stream>>>(no, Ddeg, b_conv, W_mix, b_mix, hbuf);
    k_gru<<<4096, 256, 0, stream>>>(hbuf, h_prev, W_ih, W_hh, b_ih, b_hh, W_ro, b_ro, out_h, out_o);
}

// Round 4
// 925.393 us; speedup vs baseline: 6.1570x; 1.4485x over previous
//
#include <hip/hip_runtime.h>
#include <hip/hip_bf16.h>

#define N_NODES 100000
#define N_HEDGES 20000
#define N_EDGES 800000

typedef __hip_bfloat16 bf16;
typedef __attribute__((ext_vector_type(8))) short bf16x8;
typedef __attribute__((ext_vector_type(4))) float f32x4;

__device__ __forceinline__ float b2f(bf16 v) { return __bfloat162float(v); }
__device__ __forceinline__ bf16 f2b(float v) { return __float2bfloat16(v); }

// ---------------------------------------------------------------------------
// xl[t] = x @ W_conv[t]  (both types in one pass; W in LDS; x row broadcast
// via shuffles; lane j owns output column j). xl stored bf16 (ws economy).
// ---------------------------------------------------------------------------
__global__ __launch_bounds__(256) void k_conv(const float* __restrict__ x,
                                              const float* __restrict__ Wc,
                                              bf16* __restrict__ xl) {
    __shared__ float W[2 * 64 * 64];
    for (int i = threadIdx.x; i < 2 * 64 * 64; i += 256) W[i] = Wc[i];
    __syncthreads();
    int wid = threadIdx.x >> 6, lane = threadIdx.x & 63;
    for (int row = blockIdx.x * 4 + wid; row < N_NODES; row += gridDim.x * 4) {
        float xv = x[(size_t)row * 64 + lane];
        float a0 = 0.f, a1 = 0.f;
#pragma unroll 16
        for (int k = 0; k < 64; ++k) {
            float xb = __shfl(xv, k);
            a0 += xb * W[k * 64 + lane];
            a1 += xb * W[4096 + k * 64 + lane];
        }
        xl[(size_t)row * 64 + lane] = f2b(a0);
        xl[(size_t)N_NODES * 64 + (size_t)row * 64 + lane] = f2b(a1);
    }
}

// ---------------------------------------------------------------------------
// Degrees: D[t][node] += 1, B[t][hedge] += 1 per incidence
// ---------------------------------------------------------------------------
__global__ __launch_bounds__(256) void k_deg(const int* __restrict__ node_idx,
                                             const int* __restrict__ hedge_idx,
                                             const int* __restrict__ attr,
                                             float* __restrict__ Ddeg,
                                             float* __restrict__ Bdeg) {
    int e = blockIdx.x * 256 + threadIdx.x;
    if (e < N_EDGES) {
        int t = attr[e];
        atomicAdd(&Ddeg[t * N_NODES + node_idx[e]], 1.0f);
        atomicAdd(&Bdeg[t * N_HEDGES + hedge_idx[e]], 1.0f);
    }
}

// ---------------------------------------------------------------------------
// ef[t][h] += xl[t][node]  (wave per edge, lane = feature dim)
// ---------------------------------------------------------------------------
__global__ __launch_bounds__(256) void k_ef(const int* __restrict__ node_idx,
                                            const int* __restrict__ hedge_idx,
                                            const int* __restrict__ attr,
                                            const bf16* __restrict__ xl,
                                            float* __restrict__ ef) {
    int e = blockIdx.x * 4 + (threadIdx.x >> 6);
    int lane = threadIdx.x & 63;
    if (e < N_EDGES) {
        int t = attr[e], n = node_idx[e], h = hedge_idx[e];
        float v = b2f(xl[((size_t)t * N_NODES + n) * 64 + lane]);
        atomicAdd(&ef[((size_t)t * N_HEDGES + h) * 64 + lane], v);
    }
}

// ---------------------------------------------------------------------------
// ef *= Binv  (Binv = 1/B where B>0 else 0)
// ---------------------------------------------------------------------------
__global__ __launch_bounds__(256) void k_scale(float* __restrict__ ef,
                                               const float* __restrict__ Bdeg) {
    int i = blockIdx.x * 256 + threadIdx.x;
    if (i < 2 * N_HEDGES * 64) {
        float b = Bdeg[i >> 6];
        ef[i] = (b > 0.f) ? ef[i] * (1.0f / b) : 0.f;
    }
}

// ---------------------------------------------------------------------------
// no[t][node] += ef[t][h]  (wave per edge)
// ---------------------------------------------------------------------------
__global__ __launch_bounds__(256) void k_no(const int* __restrict__ node_idx,
                                            const int* __restrict__ hedge_idx,
                                            const int* __restrict__ attr,
                                            const float* __restrict__ ef,
                                            float* __restrict__ no) {
    int e = blockIdx.x * 4 + (threadIdx.x >> 6);
    int lane = threadIdx.x & 63;
    if (e < N_EDGES) {
        int t = attr[e], n = node_idx[e], h = hedge_idx[e];
        float v = ef[((size_t)t * N_HEDGES + h) * 64 + lane];
        atomicAdd(&no[((size_t)t * N_NODES + n) * 64 + lane], v);
    }
}

// ---------------------------------------------------------------------------
// h_prev fp32 -> bf16 (for the MFMA A-operand of the W_hh GEMM)
// ---------------------------------------------------------------------------
__global__ __launch_bounds__(256) void k_cast(const float* __restrict__ src,
                                              bf16* __restrict__ dst) {
    int i = (blockIdx.x * 256 + threadIdx.x) * 4;
    if (i < N_NODES * 64) {
        float4 v = *(const float4*)&src[i];
        dst[i + 0] = f2b(v.x);
        dst[i + 1] = f2b(v.y);
        dst[i + 2] = f2b(v.z);
        dst[i + 3] = f2b(v.w);
    }
}

// ---------------------------------------------------------------------------
// h = relu( [no0*Dinv0 + bc0, no1*Dinv1 + bc1] @ W_mix + b_mix ), bf16 out
// ---------------------------------------------------------------------------
__global__ __launch_bounds__(256) void k_mix(const float* __restrict__ no,
                                             const float* __restrict__ Ddeg,
                                             const float* __restrict__ bconv,
                                             const float* __restrict__ Wm_g,
                                             const float* __restrict__ bm_g,
                                             bf16* __restrict__ hbuf16) {
    __shared__ float Wm[128 * 64];
    __shared__ float bc[128];
    __shared__ float bm[64];
    for (int i = threadIdx.x; i < 128 * 64; i += 256) Wm[i] = Wm_g[i];
    if (threadIdx.x < 128) bc[threadIdx.x] = bconv[threadIdx.x];
    if (threadIdx.x < 64) bm[threadIdx.x] = bm_g[threadIdx.x];
    __syncthreads();
    int wid = threadIdx.x >> 6, lane = threadIdx.x & 63;
    for (int row = blockIdx.x * 4 + wid; row < N_NODES; row += gridDim.x * 4) {
        float d0 = Ddeg[row], d1 = Ddeg[N_NODES + row];
        float di0 = d0 > 0.f ? 1.0f / d0 : 0.f;
        float di1 = d1 > 0.f ? 1.0f / d1 : 0.f;
        float in0 = no[(size_t)row * 64 + lane] * di0 + bc[lane];
        float in1 = no[((size_t)N_NODES + row) * 64 + lane] * di1 + bc[64 + lane];
        float acc = bm[lane];
#pragma unroll 16
        for (int k = 0; k < 64; ++k) {
            acc += __shfl(in0, k) * Wm[k * 64 + lane];
            acc += __shfl(in1, k) * Wm[(64 + k) * 64 + lane];
        }
        hbuf16[(size_t)row * 64 + lane] = f2b(fmaxf(acc, 0.f));
    }
}

// ---------------------------------------------------------------------------
// MFMA GRU: one wave per 16-row tile.
//   gi(16x192) = h @ W_ih ; gh = h_prev @ W_hh  via mfma_f32_16x16x32_bf16
// Weights packed once/block into LDS in B-fragment order (lane-major, 16B
// per lane per frag -> ds_read_b128). Previous version did 384 scalar
// ds_read_u16 PER ROW (38.4M LDS insts total) -> LDS-issue bound, 520us.
// A-frag: lane holds A[m=lane&15][k=quad*8+j] (16B contiguous from global).
// C/D: col=lane&15, row=quad*4+reg.
// ---------------------------------------------------------------------------
#define GRU_TILES (N_NODES / 16)
__global__ __launch_bounds__(256) void k_gru(const bf16* __restrict__ hbuf16,
                                             const bf16* __restrict__ hprev16,
                                             const float* __restrict__ h_prev,
                                             const float* __restrict__ Wih_g,
                                             const float* __restrict__ Whh_g,
                                             const float* __restrict__ bih_g,
                                             const float* __restrict__ bhh_g,
                                             const float* __restrict__ Wro_g,
                                             const float* __restrict__ bro_g,
                                             float* __restrict__ out_h,
                                             float* __restrict__ out_o) {
    // Wpk[mat][kt][ct][lane][j]: W[mat][kt*32 + (lane>>4)*8 + j][ct*16 + (lane&15)]
    __shared__ bf16 Wpk[2 * 2 * 12 * 64 * 8];  // 49152 B
    for (int i = threadIdx.x; i < 2 * 2 * 12 * 64 * 8; i += 256) {
        int j = i & 7;
        int r = i >> 3;
        int ln = r & 63;
        int r2 = r >> 6;
        int ct = r2 % 12;
        int r3 = r2 / 12;
        int kt = r3 & 1;
        int mat = r3 >> 1;
        int k = kt * 32 + ((ln >> 4) << 3) + j;
        int n = ct * 16 + (ln & 15);
        float v = mat == 0 ? Wih_g[k * 192 + n] : Whh_g[k * 192 + n];
        Wpk[i] = f2b(v);
    }
    __syncthreads();

    int wid = threadIdx.x >> 6, lane = threadIdx.x & 63;
    int quad = lane >> 4, l16 = lane & 15;

    // Per-lane constants: biases at col cc*16+l16 per gate, W_ro rows, b_ro.
    float bi[3][4], bh[3][4], wv[4][3];
    for (int g = 0; g < 3; ++g)
        for (int cc = 0; cc < 4; ++cc) {
            bi[g][cc] = bih_g[g * 64 + cc * 16 + l16];
            bh[g][cc] = bhh_g[g * 64 + cc * 16 + l16];
        }
    for (int cc = 0; cc < 4; ++cc)
        for (int c = 0; c < 3; ++c)
            wv[cc][c] = Wro_g[(cc * 16 + l16) * 64 + c];
    float bro0 = bro_g[0], bro1 = bro_g[1], bro2 = bro_g[2];

    int wave = blockIdx.x * 4 + wid;
    int n_waves = gridDim.x * 4;
    const f32x4 zero = {0.f, 0.f, 0.f, 0.f};

    for (int tile = wave; tile < GRU_TILES; tile += n_waves) {
        int row0 = tile * 16;
        // A-fragments (row m = row0+l16, k-halves 0..31 / 32..63)
        const bf16* ha_p = hbuf16 + (size_t)(row0 + l16) * 64 + quad * 8;
        const bf16* pa_p = hprev16 + (size_t)(row0 + l16) * 64 + quad * 8;
        bf16x8 ha0 = *(const bf16x8*)ha_p;
        bf16x8 ha1 = *(const bf16x8*)(ha_p + 32);
        bf16x8 pa0 = *(const bf16x8*)pa_p;
        bf16x8 pa1 = *(const bf16x8*)(pa_p + 32);

        float p[4][3];
#pragma unroll
        for (int rg = 0; rg < 4; ++rg) p[rg][0] = p[rg][1] = p[rg][2] = 0.f;

#pragma unroll
        for (int cc = 0; cc < 4; ++cc) {
            // B-fragment loads (ds_read_b128 each)
#define LDB(mat, kt, ct) (*(const bf16x8*)&Wpk[((((mat)*2 + (kt)) * 12 + (ct)) * 64 + lane) * 8])
            f32x4 gir = __builtin_amdgcn_mfma_f32_16x16x32_bf16(ha0, LDB(0, 0, cc), zero, 0, 0, 0);
            gir = __builtin_amdgcn_mfma_f32_16x16x32_bf16(ha1, LDB(0, 1, cc), gir, 0, 0, 0);
            f32x4 giz = __builtin_amdgcn_mfma_f32_16x16x32_bf16(ha0, LDB(0, 0, cc + 4), zero, 0, 0, 0);
            giz = __builtin_amdgcn_mfma_f32_16x16x32_bf16(ha1, LDB(0, 1, cc + 4), giz, 0, 0, 0);
            f32x4 gin = __builtin_amdgcn_mfma_f32_16x16x32_bf16(ha0, LDB(0, 0, cc + 8), zero, 0, 0, 0);
            gin = __builtin_amdgcn_mfma_f32_16x16x32_bf16(ha1, LDB(0, 1, cc + 8), gin, 0, 0, 0);
            f32x4 ghr = __builtin_amdgcn_mfma_f32_16x16x32_bf16(pa0, LDB(1, 0, cc), zero, 0, 0, 0);
            ghr = __builtin_amdgcn_mfma_f32_16x16x32_bf16(pa1, LDB(1, 1, cc), ghr, 0, 0, 0);
            f32x4 ghz = __builtin_amdgcn_mfma_f32_16x16x32_bf16(pa0, LDB(1, 0, cc + 4), zero, 0, 0, 0);
            ghz = __builtin_amdgcn_mfma_f32_16x16x32_bf16(pa1, LDB(1, 1, cc + 4), ghz, 0, 0, 0);
            f32x4 ghn = __builtin_amdgcn_mfma_f32_16x16x32_bf16(pa0, LDB(1, 0, cc + 8), zero, 0, 0, 0);
            ghn = __builtin_amdgcn_mfma_f32_16x16x32_bf16(pa1, LDB(1, 1, cc + 8), ghn, 0, 0, 0);
#undef LDB
#pragma unroll
            for (int rg = 0; rg < 4; ++rg) {
                int row = row0 + quad * 4 + rg;
                float pv = h_prev[(size_t)row * 64 + cc * 16 + l16];
                float rr = 1.f / (1.f + __expf(-(gir[rg] + bi[0][cc] + ghr[rg] + bh[0][cc])));
                float zz = 1.f / (1.f + __expf(-(giz[rg] + bi[1][cc] + ghz[rg] + bh[1][cc])));
                float nn = tanhf(gin[rg] + bi[2][cc] + rr * (ghn[rg] + bh[2][cc]));
                float hn = (1.f - zz) * nn + zz * pv;
                out_h[(size_t)row * 64 + cc * 16 + l16] = hn;
                p[rg][0] += hn * wv[cc][0];
                p[rg][1] += hn * wv[cc][1];
                p[rg][2] += hn * wv[cc][2];
            }
        }
        // reduce p across the 16 lanes of each quad group
#pragma unroll
        for (int rg = 0; rg < 4; ++rg) {
#pragma unroll
            for (int m = 1; m < 16; m <<= 1) {
                p[rg][0] += __shfl_xor(p[rg][0], m);
                p[rg][1] += __shfl_xor(p[rg][1], m);
                p[rg][2] += __shfl_xor(p[rg][2], m);
            }
        }
        if (l16 == 0) {
#pragma unroll
            for (int rg = 0; rg < 4; ++rg) {
                int row = row0 + quad * 4 + rg;
                out_o[(size_t)row * 3 + 0] = p[rg][0] + bro0;
                out_o[(size_t)row * 3 + 1] = p[rg][1] + bro1;
                out_o[(size_t)row * 3 + 2] = p[rg][2] + bro2;
            }
        }
    }
}

extern "C" void kernel_launch(void* const* d_in, const int* in_sizes, int n_in,
                              void* d_out, int out_size, void* d_ws, size_t ws_size,
                              hipStream_t stream) {
    const float* x        = (const float*)d_in[0];
    const float* h_prev   = (const float*)d_in[1];
    const int* node_idx   = (const int*)d_in[2];
    const int* hedge_idx  = (const int*)d_in[3];
    const int* edge_attr  = (const int*)d_in[4];
    const float* W_conv   = (const float*)d_in[5];
    const float* b_conv   = (const float*)d_in[6];
    const float* W_mix    = (const float*)d_in[7];
    const float* b_mix    = (const float*)d_in[8];
    const float* W_ih     = (const float*)d_in[9];
    const float* W_hh     = (const float*)d_in[10];
    const float* b_ih     = (const float*)d_in[11];
    const float* b_hh     = (const float*)d_in[12];
    const float* W_ro     = (const float*)d_in[13];
    const float* b_ro     = (const float*)d_in[14];

    // Workspace (88 MB): Ddeg[2N] | Bdeg[2H] | ef[2][H][64] | no[2][N][64] |
    // xl[2][N][64] bf16. After k_ef, xl is dead: first half becomes hbuf16
    // [N][64] bf16 (k_mix out), second half hprev16 [N][64] bf16 (k_cast out).
    char* ws    = (char*)d_ws;
    float* Ddeg = (float*)ws;
    float* Bdeg = Ddeg + 2 * N_NODES;
    float* ef   = Bdeg + 2 * N_HEDGES;
    float* no   = ef + (size_t)2 * N_HEDGES * 64;
    bf16* xl    = (bf16*)(no + (size_t)2 * N_NODES * 64);
    bf16* hbuf16  = xl;                          // alias: valid after k_ef
    bf16* hprev16 = xl + (size_t)N_NODES * 64;   // alias: valid after k_ef

    size_t zero_bytes = ((size_t)2 * N_NODES + 2 * N_HEDGES +
                         (size_t)2 * N_HEDGES * 64 + (size_t)2 * N_NODES * 64) *
                        sizeof(float);
    hipMemsetAsync(d_ws, 0, zero_bytes, stream);

    float* out_h = (float*)d_out;
    float* out_o = out_h + (size_t)N_NODES * 64;

    k_conv<<<2048, 256, 0, stream>>>(x, W_conv, xl);
    k_deg<<<(N_EDGES + 255) / 256, 256, 0, stream>>>(node_idx, hedge_idx, edge_attr, Ddeg, Bdeg);
    k_ef<<<N_EDGES / 4, 256, 0, stream>>>(node_idx, hedge_idx, edge_attr, xl, ef);
    k_scale<<<(2 * N_HEDGES * 64 + 255) / 256, 256, 0, stream>>>(ef, Bdeg);
    k_cast<<<(N_NODES * 64 / 4 + 255) / 256, 256, 0, stream>>>(h_prev, hprev16);
    k_no<<<N_EDGES / 4, 256, 0, stream>>>(node_idx, hedge_idx, edge_attr, ef, no);
    k_mix<<<2048, 256, 0, stream>>>(no, Ddeg, b_conv, W_mix, b_mix, hbuf16);
    k_gru<<<512, 256, 0, stream>>>(hbuf16, hprev16, h_prev, W_ih, W_hh, b_ih, b_hh,
                                   W_ro, b_ro, out_h, out_o);
}

// Round 5
// 649.643 us; speedup vs baseline: 8.7704x; 1.4245x over previous
//
#include <hip/hip_runtime.h>
#include <hip/hip_bf16.h>

#define N_NODES 100000
#define N_HEDGES 20000
#define N_EDGES 800000

typedef __hip_bfloat16 bf16;
typedef __attribute__((ext_vector_type(8))) short bf16x8;
typedef __attribute__((ext_vector_type(4))) float f32x4;

__device__ __forceinline__ float b2f(bf16 v) { return __bfloat162float(v); }
__device__ __forceinline__ bf16 f2b(float v) { return __float2bfloat16(v); }
__device__ __forceinline__ short f2s(float v) {
    bf16 b = __float2bfloat16(v);
    return *reinterpret_cast<short*>(&b);
}
__device__ __forceinline__ bf16x8 pack8(float4 a, float4 b) {
    bf16x8 r = {f2s(a.x), f2s(a.y), f2s(a.z), f2s(a.w),
                f2s(b.x), f2s(b.y), f2s(b.z), f2s(b.w)};
    return r;
}

// ---------------------------------------------------------------------------
// MFMA conv: xl[t] = x @ W_conv[t], one wave per 16-row tile, both types.
// A-frag: lane holds A[m=lane&15][k=(lane>>4)*8+j] (fp32->bf16 inline).
// B packed once/block into LDS in B-frag order -> ds_read_b128.
// C/D: col=lane&15, row=(lane>>4)*4+reg.
// ---------------------------------------------------------------------------
__global__ __launch_bounds__(256) void k_conv(const float* __restrict__ x,
                                              const float* __restrict__ Wc,
                                              bf16* __restrict__ xl) {
    // Wpk[t][kt][ct][lane][j] = Wc[t][kt*32+(lane>>4)*8+j][ct*16+(lane&15)]
    __shared__ bf16 Wpk[2 * 2 * 4 * 64 * 8];  // 8192 elems, 16 KB
    for (int i = threadIdx.x; i < 2 * 2 * 4 * 64 * 8; i += 256) {
        int j = i & 7;
        int ln = (i >> 3) & 63;
        int r2 = i >> 9;          // (t*2+kt)*4 + ct
        int ct = r2 & 3;
        int kt = (r2 >> 2) & 1;
        int t = r2 >> 3;
        int k = kt * 32 + ((ln >> 4) << 3) + j;
        int n = ct * 16 + (ln & 15);
        Wpk[i] = f2b(Wc[((size_t)t * 64 + k) * 64 + n]);
    }
    __syncthreads();
    int wid = threadIdx.x >> 6, lane = threadIdx.x & 63;
    int quad = lane >> 4, l16 = lane & 15;
    int wave = blockIdx.x * 4 + wid, n_waves = gridDim.x * 4;
    const f32x4 zero = {0.f, 0.f, 0.f, 0.f};
    for (int tile = wave; tile < N_NODES / 16; tile += n_waves) {
        int row0 = tile * 16;
        const float* xp = x + (size_t)(row0 + l16) * 64 + quad * 8;
        bf16x8 a0 = pack8(*(const float4*)xp, *(const float4*)(xp + 4));
        bf16x8 a1 = pack8(*(const float4*)(xp + 32), *(const float4*)(xp + 36));
#define LDBC(t, kt, ct) (*(const bf16x8*)&Wpk[((((t)*2 + (kt)) * 4 + (ct)) * 64 + lane) * 8])
#pragma unroll
        for (int t = 0; t < 2; ++t) {
#pragma unroll
            for (int ct = 0; ct < 4; ++ct) {
                f32x4 acc = __builtin_amdgcn_mfma_f32_16x16x32_bf16(a0, LDBC(t, 0, ct), zero, 0, 0, 0);
                acc = __builtin_amdgcn_mfma_f32_16x16x32_bf16(a1, LDBC(t, 1, ct), acc, 0, 0, 0);
#pragma unroll
                for (int rg = 0; rg < 4; ++rg) {
                    int row = row0 + quad * 4 + rg;
                    xl[(size_t)t * N_NODES * 64 + (size_t)row * 64 + ct * 16 + l16] = f2b(acc[rg]);
                }
            }
        }
#undef LDBC
    }
}

// ---------------------------------------------------------------------------
// Degrees: D[t][node] += 1, B[t][hedge] += 1 per incidence
// ---------------------------------------------------------------------------
__global__ __launch_bounds__(256) void k_deg(const int* __restrict__ node_idx,
                                             const int* __restrict__ hedge_idx,
                                             const int* __restrict__ attr,
                                             float* __restrict__ Ddeg,
                                             float* __restrict__ Bdeg) {
    int e = blockIdx.x * 256 + threadIdx.x;
    if (e < N_EDGES) {
        int t = attr[e];
        atomicAdd(&Ddeg[t * N_NODES + node_idx[e]], 1.0f);
        atomicAdd(&Bdeg[t * N_HEDGES + hedge_idx[e]], 1.0f);
    }
}

// ---------------------------------------------------------------------------
// ef[t][h] += xl[t][node]  (wave per edge, lane = feature dim)
// ---------------------------------------------------------------------------
__global__ __launch_bounds__(256) void k_ef(const int* __restrict__ node_idx,
                                            const int* __restrict__ hedge_idx,
                                            const int* __restrict__ attr,
                                            const bf16* __restrict__ xl,
                                            float* __restrict__ ef) {
    int e = blockIdx.x * 4 + (threadIdx.x >> 6);
    int lane = threadIdx.x & 63;
    if (e < N_EDGES) {
        int t = attr[e], n = node_idx[e], h = hedge_idx[e];
        float v = b2f(xl[((size_t)t * N_NODES + n) * 64 + lane]);
        atomicAdd(&ef[((size_t)t * N_HEDGES + h) * 64 + lane], v);
    }
}

// ---------------------------------------------------------------------------
// ef *= Binv  (Binv = 1/B where B>0 else 0)
// ---------------------------------------------------------------------------
__global__ __launch_bounds__(256) void k_scale(float* __restrict__ ef,
                                               const float* __restrict__ Bdeg) {
    int i = blockIdx.x * 256 + threadIdx.x;
    if (i < 2 * N_HEDGES * 64) {
        float b = Bdeg[i >> 6];
        ef[i] = (b > 0.f) ? ef[i] * (1.0f / b) : 0.f;
    }
}

// ---------------------------------------------------------------------------
// no[t][node] += ef[t][h]  (wave per edge)
// ---------------------------------------------------------------------------
__global__ __launch_bounds__(256) void k_no(const int* __restrict__ node_idx,
                                            const int* __restrict__ hedge_idx,
                                            const int* __restrict__ attr,
                                            const float* __restrict__ ef,
                                            float* __restrict__ no) {
    int e = blockIdx.x * 4 + (threadIdx.x >> 6);
    int lane = threadIdx.x & 63;
    if (e < N_EDGES) {
        int t = attr[e], n = node_idx[e], h = hedge_idx[e];
        float v = ef[((size_t)t * N_HEDGES + h) * 64 + lane];
        atomicAdd(&no[((size_t)t * N_NODES + n) * 64 + lane], v);
    }
}

// ---------------------------------------------------------------------------
// MFMA mix: h = relu([no0*Dinv0+bc0, no1*Dinv1+bc1] @ W_mix + b_mix), bf16.
// K=128 -> 4 k-fragments; A built inline (fused Dinv scale + b_conv add,
// fp32->bf16); acc seeded with b_mix; 16 MFMA per 16-row tile.
// ---------------------------------------------------------------------------
__global__ __launch_bounds__(256) void k_mix(const float* __restrict__ no,
                                             const float* __restrict__ Ddeg,
                                             const float* __restrict__ bconv,
                                             const float* __restrict__ Wm_g,
                                             const float* __restrict__ bm_g,
                                             bf16* __restrict__ hbuf16) {
    // Wpk[kt][ct][lane][j] = Wm[kt*32+(lane>>4)*8+j][ct*16+(lane&15)]
    __shared__ bf16 Wpk[4 * 4 * 64 * 8];  // 8192 elems, 16 KB
    for (int i = threadIdx.x; i < 4 * 4 * 64 * 8; i += 256) {
        int j = i & 7;
        int ln = (i >> 3) & 63;
        int r2 = i >> 9;  // kt*4 + ct
        int ct = r2 & 3;
        int kt = r2 >> 2;
        int k = kt * 32 + ((ln >> 4) << 3) + j;
        int n = ct * 16 + (ln & 15);
        Wpk[i] = f2b(Wm_g[(size_t)k * 64 + n]);
    }
    __syncthreads();
    int wid = threadIdx.x >> 6, lane = threadIdx.x & 63;
    int quad = lane >> 4, l16 = lane & 15;
    // per-lane bias constants: bcv[kt][j] = bconv[kt*32 + quad*8 + j]
    float bcv[4][8];
#pragma unroll
    for (int kt = 0; kt < 4; ++kt)
#pragma unroll
        for (int j = 0; j < 8; ++j) bcv[kt][j] = bconv[kt * 32 + quad * 8 + j];
    float bmv[4];
#pragma unroll
    for (int ct = 0; ct < 4; ++ct) bmv[ct] = bm_g[ct * 16 + l16];

    int wave = blockIdx.x * 4 + wid, n_waves = gridDim.x * 4;
    for (int tile = wave; tile < N_NODES / 16; tile += n_waves) {
        int row0 = tile * 16;
        int arow = row0 + l16;
        float d0 = Ddeg[arow], d1 = Ddeg[N_NODES + arow];
        float di0 = d0 > 0.f ? 1.0f / d0 : 0.f;
        float di1 = d1 > 0.f ? 1.0f / d1 : 0.f;
        bf16x8 af[4];
#pragma unroll
        for (int kt = 0; kt < 4; ++kt) {
            const float* src = (kt < 2)
                ? no + (size_t)arow * 64 + kt * 32 + quad * 8
                : no + (size_t)N_NODES * 64 + (size_t)arow * 64 + (kt - 2) * 32 + quad * 8;
            float di = (kt < 2) ? di0 : di1;
            float4 u0 = *(const float4*)src;
            float4 u1 = *(const float4*)(src + 4);
            bf16x8 t;
            t[0] = f2s(u0.x * di + bcv[kt][0]);
            t[1] = f2s(u0.y * di + bcv[kt][1]);
            t[2] = f2s(u0.z * di + bcv[kt][2]);
            t[3] = f2s(u0.w * di + bcv[kt][3]);
            t[4] = f2s(u1.x * di + bcv[kt][4]);
            t[5] = f2s(u1.y * di + bcv[kt][5]);
            t[6] = f2s(u1.z * di + bcv[kt][6]);
            t[7] = f2s(u1.w * di + bcv[kt][7]);
            af[kt] = t;
        }
#define LDBM(kt, ct) (*(const bf16x8*)&Wpk[(((kt)*4 + (ct)) * 64 + lane) * 8])
#pragma unroll
        for (int ct = 0; ct < 4; ++ct) {
            f32x4 acc = {bmv[ct], bmv[ct], bmv[ct], bmv[ct]};
#pragma unroll
            for (int kt = 0; kt < 4; ++kt)
                acc = __builtin_amdgcn_mfma_f32_16x16x32_bf16(af[kt], LDBM(kt, ct), acc, 0, 0, 0);
#pragma unroll
            for (int rg = 0; rg < 4; ++rg) {
                int row = row0 + quad * 4 + rg;
                hbuf16[(size_t)row * 64 + ct * 16 + l16] = f2b(fmaxf(acc[rg], 0.f));
            }
        }
#undef LDBM
    }
}

// ---------------------------------------------------------------------------
// MFMA GRU: one wave per 16-row tile; h_prev cast fp32->bf16 inline.
// ---------------------------------------------------------------------------
#define GRU_TILES (N_NODES / 16)
__global__ __launch_bounds__(256) void k_gru(const bf16* __restrict__ hbuf16,
                                             const float* __restrict__ h_prev,
                                             const float* __restrict__ Wih_g,
                                             const float* __restrict__ Whh_g,
                                             const float* __restrict__ bih_g,
                                             const float* __restrict__ bhh_g,
                                             const float* __restrict__ Wro_g,
                                             const float* __restrict__ bro_g,
                                             float* __restrict__ out_h,
                                             float* __restrict__ out_o) {
    // Wpk[mat][kt][ct][lane][j]: W[mat][kt*32 + (lane>>4)*8 + j][ct*16 + (lane&15)]
    __shared__ bf16 Wpk[2 * 2 * 12 * 64 * 8];  // 49152 B
    for (int i = threadIdx.x; i < 2 * 2 * 12 * 64 * 8; i += 256) {
        int j = i & 7;
        int r = i >> 3;
        int ln = r & 63;
        int r2 = r >> 6;
        int ct = r2 % 12;
        int r3 = r2 / 12;
        int kt = r3 & 1;
        int mat = r3 >> 1;
        int k = kt * 32 + ((ln >> 4) << 3) + j;
        int n = ct * 16 + (ln & 15);
        float v = mat == 0 ? Wih_g[k * 192 + n] : Whh_g[k * 192 + n];
        Wpk[i] = f2b(v);
    }
    __syncthreads();

    int wid = threadIdx.x >> 6, lane = threadIdx.x & 63;
    int quad = lane >> 4, l16 = lane & 15;

    float bi[3][4], bh[3][4], wv[4][3];
    for (int g = 0; g < 3; ++g)
        for (int cc = 0; cc < 4; ++cc) {
            bi[g][cc] = bih_g[g * 64 + cc * 16 + l16];
            bh[g][cc] = bhh_g[g * 64 + cc * 16 + l16];
        }
    for (int cc = 0; cc < 4; ++cc)
        for (int c = 0; c < 3; ++c)
            wv[cc][c] = Wro_g[(cc * 16 + l16) * 64 + c];
    float bro0 = bro_g[0], bro1 = bro_g[1], bro2 = bro_g[2];

    int wave = blockIdx.x * 4 + wid;
    int n_waves = gridDim.x * 4;
    const f32x4 zero = {0.f, 0.f, 0.f, 0.f};

    for (int tile = wave; tile < GRU_TILES; tile += n_waves) {
        int row0 = tile * 16;
        const bf16* ha_p = hbuf16 + (size_t)(row0 + l16) * 64 + quad * 8;
        bf16x8 ha0 = *(const bf16x8*)ha_p;
        bf16x8 ha1 = *(const bf16x8*)(ha_p + 32);
        const float* pp = h_prev + (size_t)(row0 + l16) * 64 + quad * 8;
        bf16x8 pa0 = pack8(*(const float4*)pp, *(const float4*)(pp + 4));
        bf16x8 pa1 = pack8(*(const float4*)(pp + 32), *(const float4*)(pp + 36));

        float p[4][3];
#pragma unroll
        for (int rg = 0; rg < 4; ++rg) p[rg][0] = p[rg][1] = p[rg][2] = 0.f;

#pragma unroll
        for (int cc = 0; cc < 4; ++cc) {
#define LDB(mat, kt, ct) (*(const bf16x8*)&Wpk[((((mat)*2 + (kt)) * 12 + (ct)) * 64 + lane) * 8])
            f32x4 gir = __builtin_amdgcn_mfma_f32_16x16x32_bf16(ha0, LDB(0, 0, cc), zero, 0, 0, 0);
            gir = __builtin_amdgcn_mfma_f32_16x16x32_bf16(ha1, LDB(0, 1, cc), gir, 0, 0, 0);
            f32x4 giz = __builtin_amdgcn_mfma_f32_16x16x32_bf16(ha0, LDB(0, 0, cc + 4), zero, 0, 0, 0);
            giz = __builtin_amdgcn_mfma_f32_16x16x32_bf16(ha1, LDB(0, 1, cc + 4), giz, 0, 0, 0);
            f32x4 gin = __builtin_amdgcn_mfma_f32_16x16x32_bf16(ha0, LDB(0, 0, cc + 8), zero, 0, 0, 0);
            gin = __builtin_amdgcn_mfma_f32_16x16x32_bf16(ha1, LDB(0, 1, cc + 8), gin, 0, 0, 0);
            f32x4 ghr = __builtin_amdgcn_mfma_f32_16x16x32_bf16(pa0, LDB(1, 0, cc), zero, 0, 0, 0);
            ghr = __builtin_amdgcn_mfma_f32_16x16x32_bf16(pa1, LDB(1, 1, cc), ghr, 0, 0, 0);
            f32x4 ghz = __builtin_amdgcn_mfma_f32_16x16x32_bf16(pa0, LDB(1, 0, cc + 4), zero, 0, 0, 0);
            ghz = __builtin_amdgcn_mfma_f32_16x16x32_bf16(pa1, LDB(1, 1, cc + 4), ghz, 0, 0, 0);
            f32x4 ghn = __builtin_amdgcn_mfma_f32_16x16x32_bf16(pa0, LDB(1, 0, cc + 8), zero, 0, 0, 0);
            ghn = __builtin_amdgcn_mfma_f32_16x16x32_bf16(pa1, LDB(1, 1, cc + 8), ghn, 0, 0, 0);
#undef LDB
#pragma unroll
            for (int rg = 0; rg < 4; ++rg) {
                int row = row0 + quad * 4 + rg;
                float pv = h_prev[(size_t)row * 64 + cc * 16 + l16];
                float rr = 1.f / (1.f + __expf(-(gir[rg] + bi[0][cc] + ghr[rg] + bh[0][cc])));
                float zz = 1.f / (1.f + __expf(-(giz[rg] + bi[1][cc] + ghz[rg] + bh[1][cc])));
                float nn = tanhf(gin[rg] + bi[2][cc] + rr * (ghn[rg] + bh[2][cc]));
                float hn = (1.f - zz) * nn + zz * pv;
                out_h[(size_t)row * 64 + cc * 16 + l16] = hn;
                p[rg][0] += hn * wv[cc][0];
                p[rg][1] += hn * wv[cc][1];
                p[rg][2] += hn * wv[cc][2];
            }
        }
#pragma unroll
        for (int rg = 0; rg < 4; ++rg) {
#pragma unroll
            for (int m = 1; m < 16; m <<= 1) {
                p[rg][0] += __shfl_xor(p[rg][0], m);
                p[rg][1] += __shfl_xor(p[rg][1], m);
                p[rg][2] += __shfl_xor(p[rg][2], m);
            }
        }
        if (l16 == 0) {
#pragma unroll
            for (int rg = 0; rg < 4; ++rg) {
                int row = row0 + quad * 4 + rg;
                out_o[(size_t)row * 3 + 0] = p[rg][0] + bro0;
                out_o[(size_t)row * 3 + 1] = p[rg][1] + bro1;
                out_o[(size_t)row * 3 + 2] = p[rg][2] + bro2;
            }
        }
    }
}

extern "C" void kernel_launch(void* const* d_in, const int* in_sizes, int n_in,
                              void* d_out, int out_size, void* d_ws, size_t ws_size,
                              hipStream_t stream) {
    const float* x        = (const float*)d_in[0];
    const float* h_prev   = (const float*)d_in[1];
    const int* node_idx   = (const int*)d_in[2];
    const int* hedge_idx  = (const int*)d_in[3];
    const int* edge_attr  = (const int*)d_in[4];
    const float* W_conv   = (const float*)d_in[5];
    const float* b_conv   = (const float*)d_in[6];
    const float* W_mix    = (const float*)d_in[7];
    const float* b_mix    = (const float*)d_in[8];
    const float* W_ih     = (const float*)d_in[9];
    const float* W_hh     = (const float*)d_in[10];
    const float* b_ih     = (const float*)d_in[11];
    const float* b_hh     = (const float*)d_in[12];
    const float* W_ro     = (const float*)d_in[13];
    const float* b_ro     = (const float*)d_in[14];

    // Workspace (88 MB): Ddeg[2N] | Bdeg[2H] | ef[2][H][64] | no[2][N][64] |
    // xl[2][N][64] bf16. After k_ef, xl is dead: first half becomes hbuf16.
    char* ws    = (char*)d_ws;
    float* Ddeg = (float*)ws;
    float* Bdeg = Ddeg + 2 * N_NODES;
    float* ef   = Bdeg + 2 * N_HEDGES;
    float* no   = ef + (size_t)2 * N_HEDGES * 64;
    bf16* xl    = (bf16*)(no + (size_t)2 * N_NODES * 64);
    bf16* hbuf16 = xl;  // alias: valid after k_ef

    size_t zero_bytes = ((size_t)2 * N_NODES + 2 * N_HEDGES +
                         (size_t)2 * N_HEDGES * 64 + (size_t)2 * N_NODES * 64) *
                        sizeof(float);
    hipMemsetAsync(d_ws, 0, zero_bytes, stream);

    float* out_h = (float*)d_out;
    float* out_o = out_h + (size_t)N_NODES * 64;

    k_conv<<<512, 256, 0, stream>>>(x, W_conv, xl);
    k_deg<<<(N_EDGES + 255) / 256, 256, 0, stream>>>(node_idx, hedge_idx, edge_attr, Ddeg, Bdeg);
    k_ef<<<N_EDGES / 4, 256, 0, stream>>>(node_idx, hedge_idx, edge_attr, xl, ef);
    k_scale<<<(2 * N_HEDGES * 64 + 255) / 256, 256, 0, stream>>>(ef, Bdeg);
    k_no<<<N_EDGES / 4, 256, 0, stream>>>(node_idx, hedge_idx, edge_attr, ef, no);
    k_mix<<<512, 256, 0, stream>>>(no, Ddeg, b_conv, W_mix, b_mix, hbuf16);
    k_gru<<<512, 256, 0, stream>>>(hbuf16, h_prev, W_ih, W_hh, b_ih, b_hh,
                                   W_ro, b_ro, out_h, out_o);
}

// Round 6
// 512.832 us; speedup vs baseline: 11.1101x; 1.2668x over previous
//
#include <hip/hip_runtime.h>
#include <hip/hip_bf16.h>

#define N_NODES 100000
#define N_HEDGES 20000
#define N_EDGES 800000
#define HSEG (2 * N_HEDGES)            // 40000 hedge segments (t,h)
#define NSEG (2 * N_NODES)             // 200000 node segments (t,n)
#define MSEG (HSEG + NSEG)             // 240000 joint counters
#define SCAN_BLOCKS ((MSEG + 255) / 256)  // 938

typedef __hip_bfloat16 bf16;
typedef __attribute__((ext_vector_type(8))) short bf16x8;
typedef __attribute__((ext_vector_type(4))) float f32x4;

__device__ __forceinline__ float b2f(bf16 v) { return __bfloat162float(v); }
__device__ __forceinline__ bf16 f2b(float v) { return __float2bfloat16(v); }
__device__ __forceinline__ short f2s(float v) {
    bf16 b = __float2bfloat16(v);
    return *reinterpret_cast<short*>(&b);
}
__device__ __forceinline__ bf16x8 pack8(float4 a, float4 b) {
    bf16x8 r = {f2s(a.x), f2s(a.y), f2s(a.z), f2s(a.w),
                f2s(b.x), f2s(b.y), f2s(b.z), f2s(b.w)};
    return r;
}

// ---------------------------------------------------------------------------
// MFMA conv: xl[t] = x @ W_conv[t], one wave per 16-row tile, both types.
// ---------------------------------------------------------------------------
__global__ __launch_bounds__(256) void k_conv(const float* __restrict__ x,
                                              const float* __restrict__ Wc,
                                              bf16* __restrict__ xl) {
    __shared__ bf16 Wpk[2 * 2 * 4 * 64 * 8];  // 16 KB
    for (int i = threadIdx.x; i < 2 * 2 * 4 * 64 * 8; i += 256) {
        int j = i & 7;
        int ln = (i >> 3) & 63;
        int r2 = i >> 9;
        int ct = r2 & 3;
        int kt = (r2 >> 2) & 1;
        int t = r2 >> 3;
        int k = kt * 32 + ((ln >> 4) << 3) + j;
        int n = ct * 16 + (ln & 15);
        Wpk[i] = f2b(Wc[((size_t)t * 64 + k) * 64 + n]);
    }
    __syncthreads();
    int wid = threadIdx.x >> 6, lane = threadIdx.x & 63;
    int quad = lane >> 4, l16 = lane & 15;
    int wave = blockIdx.x * 4 + wid, n_waves = gridDim.x * 4;
    const f32x4 zero = {0.f, 0.f, 0.f, 0.f};
    for (int tile = wave; tile < N_NODES / 16; tile += n_waves) {
        int row0 = tile * 16;
        const float* xp = x + (size_t)(row0 + l16) * 64 + quad * 8;
        bf16x8 a0 = pack8(*(const float4*)xp, *(const float4*)(xp + 4));
        bf16x8 a1 = pack8(*(const float4*)(xp + 32), *(const float4*)(xp + 36));
#define LDBC(t, kt, ct) (*(const bf16x8*)&Wpk[((((t)*2 + (kt)) * 4 + (ct)) * 64 + lane) * 8])
#pragma unroll
        for (int t = 0; t < 2; ++t) {
#pragma unroll
            for (int ct = 0; ct < 4; ++ct) {
                f32x4 acc = __builtin_amdgcn_mfma_f32_16x16x32_bf16(a0, LDBC(t, 0, ct), zero, 0, 0, 0);
                acc = __builtin_amdgcn_mfma_f32_16x16x32_bf16(a1, LDBC(t, 1, ct), acc, 0, 0, 0);
#pragma unroll
                for (int rg = 0; rg < 4; ++rg) {
                    int row = row0 + quad * 4 + rg;
                    xl[(size_t)t * N_NODES * 64 + (size_t)row * 64 + ct * 16 + l16] = f2b(acc[rg]);
                }
            }
        }
#undef LDBC
    }
}

// ---------------------------------------------------------------------------
// Counting-sort phase 1: joint histogram.
// cnt[0..HSEG): (t,h) counts; cnt[HSEG..MSEG): (t,n) counts.
// ---------------------------------------------------------------------------
__global__ __launch_bounds__(256) void k_hist(const int* __restrict__ node_idx,
                                              const int* __restrict__ hedge_idx,
                                              const int* __restrict__ attr,
                                              int* __restrict__ cnt) {
    int e = blockIdx.x * 256 + threadIdx.x;
    if (e < N_EDGES) {
        int t = attr[e];
        atomicAdd(&cnt[t * N_HEDGES + hedge_idx[e]], 1);
        atomicAdd(&cnt[HSEG + t * N_NODES + node_idx[e]], 1);
    }
}

// ---------------------------------------------------------------------------
// Scan 1/3: per-block exclusive scan of cnt -> off (partial), block sums.
// ---------------------------------------------------------------------------
__global__ __launch_bounds__(256) void k_scan1(const int* __restrict__ cnt,
                                               int* __restrict__ off,
                                               int* __restrict__ bsum) {
    __shared__ int s[256];
    int gid = blockIdx.x * 256 + threadIdx.x;
    int v = (gid < MSEG) ? cnt[gid] : 0;
    s[threadIdx.x] = v;
    __syncthreads();
    for (int o = 1; o < 256; o <<= 1) {
        int t = (threadIdx.x >= o) ? s[threadIdx.x - o] : 0;
        __syncthreads();
        s[threadIdx.x] += t;
        __syncthreads();
    }
    if (gid < MSEG) off[gid] = s[threadIdx.x] - v;  // exclusive within block
    if (threadIdx.x == 255) bsum[blockIdx.x] = s[255];
}

// ---------------------------------------------------------------------------
// Scan 2/3: exclusive scan of the block sums (single block).
// ---------------------------------------------------------------------------
__global__ __launch_bounds__(1024) void k_scan2(int* __restrict__ bsum) {
    __shared__ int s[1024];
    int tid = threadIdx.x;
    int v = (tid < SCAN_BLOCKS) ? bsum[tid] : 0;
    s[tid] = v;
    __syncthreads();
    for (int o = 1; o < 1024; o <<= 1) {
        int t = (tid >= o) ? s[tid - o] : 0;
        __syncthreads();
        s[tid] += t;
        __syncthreads();
    }
    if (tid < SCAN_BLOCKS) bsum[tid] = s[tid] - v;  // exclusive
}

// ---------------------------------------------------------------------------
// Scan 3/3: add block offsets; produce final off + cursor copy; off[MSEG].
// ---------------------------------------------------------------------------
__global__ __launch_bounds__(256) void k_scan3(int* __restrict__ off,
                                               const int* __restrict__ bsum,
                                               int* __restrict__ cursor) {
    int gid = blockIdx.x * 256 + threadIdx.x;
    if (gid < MSEG) {
        int v = off[gid] + bsum[blockIdx.x];
        off[gid] = v;
        cursor[gid] = v;
    }
    if (gid == 0) off[MSEG] = 2 * N_EDGES;
}

// ---------------------------------------------------------------------------
// Counting-sort phase 2: place each edge in both segment lists.
// Hedge-side entries store the flat xl row (t*N_NODES+n);
// node-side entries store the flat ef row (t*N_HEDGES+h).
// ---------------------------------------------------------------------------
__global__ __launch_bounds__(256) void k_scatter(const int* __restrict__ node_idx,
                                                 const int* __restrict__ hedge_idx,
                                                 const int* __restrict__ attr,
                                                 int* __restrict__ cursor,
                                                 int* __restrict__ sortedAll) {
    int e = blockIdx.x * 256 + threadIdx.x;
    if (e < N_EDGES) {
        int t = attr[e], n = node_idx[e], h = hedge_idx[e];
        int p1 = atomicAdd(&cursor[t * N_HEDGES + h], 1);
        sortedAll[p1] = t * N_NODES + n;
        int p2 = atomicAdd(&cursor[HSEG + t * N_NODES + n], 1);
        sortedAll[p2] = t * N_HEDGES + h;
    }
}

// ---------------------------------------------------------------------------
// CSR node->hedge: ef[t][h] = (1/B) * sum xl[t][n] over segment.
// B == segment length. One wave per segment, lane = feature. Single write.
// ---------------------------------------------------------------------------
__global__ __launch_bounds__(256) void k_ef2(const int* __restrict__ off,
                                             const int* __restrict__ sortedAll,
                                             const bf16* __restrict__ xl,
                                             bf16* __restrict__ ef16) {
    int wid = threadIdx.x >> 6, lane = threadIdx.x & 63;
    int s = blockIdx.x * 4 + wid;
    if (s >= HSEG) return;
    int beg = off[s], end = off[s + 1];
    float sum0 = 0.f, sum1 = 0.f;
    int i = beg;
    for (; i + 1 < end; i += 2) {
        int r0 = sortedAll[i], r1 = sortedAll[i + 1];
        sum0 += b2f(xl[(size_t)r0 * 64 + lane]);
        sum1 += b2f(xl[(size_t)r1 * 64 + lane]);
    }
    if (i < end) sum0 += b2f(xl[(size_t)sortedAll[i] * 64 + lane]);
    int c = end - beg;
    float scale = c > 0 ? 1.0f / (float)c : 0.f;
    ef16[(size_t)s * 64 + lane] = f2b((sum0 + sum1) * scale);
}

// ---------------------------------------------------------------------------
// CSR hedge->node: mixin[t][n] = (1/D) * sum ef[t][h] + b_conv[t].
// D == segment length. bf16 out in k_mix's A-operand layout.
// ---------------------------------------------------------------------------
__global__ __launch_bounds__(256) void k_no2(const int* __restrict__ off,
                                             const int* __restrict__ sortedAll,
                                             const bf16* __restrict__ ef16,
                                             const float* __restrict__ bconv,
                                             bf16* __restrict__ mixin16) {
    int wid = threadIdx.x >> 6, lane = threadIdx.x & 63;
    int j = blockIdx.x * 4 + wid;
    if (j >= NSEG) return;
    int s = HSEG + j;
    int beg = off[s], end = off[s + 1];
    float sum0 = 0.f, sum1 = 0.f;
    int i = beg;
    for (; i + 1 < end; i += 2) {
        int r0 = sortedAll[i], r1 = sortedAll[i + 1];
        sum0 += b2f(ef16[(size_t)r0 * 64 + lane]);
        sum1 += b2f(ef16[(size_t)r1 * 64 + lane]);
    }
    if (i < end) sum0 += b2f(ef16[(size_t)sortedAll[i] * 64 + lane]);
    int c = end - beg;
    float scale = c > 0 ? 1.0f / (float)c : 0.f;
    int t = j / N_NODES;
    float bc = bconv[t * 64 + lane];
    mixin16[(size_t)j * 64 + lane] = f2b((sum0 + sum1) * scale + bc);
}

// ---------------------------------------------------------------------------
// MFMA mix: h = relu(mixin @ W_mix + b_mix), bf16 out. K=128 (4 k-frags).
// mixin already includes Dinv scaling + b_conv (fused in k_no2).
// ---------------------------------------------------------------------------
__global__ __launch_bounds__(256) void k_mix(const bf16* __restrict__ mixin16,
                                             const float* __restrict__ Wm_g,
                                             const float* __restrict__ bm_g,
                                             bf16* __restrict__ hbuf16) {
    __shared__ bf16 Wpk[4 * 4 * 64 * 8];  // 16 KB
    for (int i = threadIdx.x; i < 4 * 4 * 64 * 8; i += 256) {
        int j = i & 7;
        int ln = (i >> 3) & 63;
        int r2 = i >> 9;
        int ct = r2 & 3;
        int kt = r2 >> 2;
        int k = kt * 32 + ((ln >> 4) << 3) + j;
        int n = ct * 16 + (ln & 15);
        Wpk[i] = f2b(Wm_g[(size_t)k * 64 + n]);
    }
    __syncthreads();
    int wid = threadIdx.x >> 6, lane = threadIdx.x & 63;
    int quad = lane >> 4, l16 = lane & 15;
    float bmv[4];
#pragma unroll
    for (int ct = 0; ct < 4; ++ct) bmv[ct] = bm_g[ct * 16 + l16];

    int wave = blockIdx.x * 4 + wid, n_waves = gridDim.x * 4;
    for (int tile = wave; tile < N_NODES / 16; tile += n_waves) {
        int row0 = tile * 16;
        int arow = row0 + l16;
        bf16x8 af[4];
#pragma unroll
        for (int kt = 0; kt < 4; ++kt) {
            const bf16* src = (kt < 2)
                ? mixin16 + (size_t)arow * 64 + kt * 32 + quad * 8
                : mixin16 + ((size_t)N_NODES + arow) * 64 + (kt - 2) * 32 + quad * 8;
            af[kt] = *(const bf16x8*)src;
        }
#define LDBM(kt, ct) (*(const bf16x8*)&Wpk[(((kt)*4 + (ct)) * 64 + lane) * 8])
#pragma unroll
        for (int ct = 0; ct < 4; ++ct) {
            f32x4 acc = {bmv[ct], bmv[ct], bmv[ct], bmv[ct]};
#pragma unroll
            for (int kt = 0; kt < 4; ++kt)
                acc = __builtin_amdgcn_mfma_f32_16x16x32_bf16(af[kt], LDBM(kt, ct), acc, 0, 0, 0);
#pragma unroll
            for (int rg = 0; rg < 4; ++rg) {
                int row = row0 + quad * 4 + rg;
                hbuf16[(size_t)row * 64 + ct * 16 + l16] = f2b(fmaxf(acc[rg], 0.f));
            }
        }
#undef LDBM
    }
}

// ---------------------------------------------------------------------------
// MFMA GRU: one wave per 16-row tile; h_prev cast fp32->bf16 inline.
// ---------------------------------------------------------------------------
#define GRU_TILES (N_NODES / 16)
__global__ __launch_bounds__(256) void k_gru(const bf16* __restrict__ hbuf16,
                                             const float* __restrict__ h_prev,
                                             const float* __restrict__ Wih_g,
                                             const float* __restrict__ Whh_g,
                                             const float* __restrict__ bih_g,
                                             const float* __restrict__ bhh_g,
                                             const float* __restrict__ Wro_g,
                                             const float* __restrict__ bro_g,
                                             float* __restrict__ out_h,
                                             float* __restrict__ out_o) {
    __shared__ bf16 Wpk[2 * 2 * 12 * 64 * 8];  // 48 KB
    for (int i = threadIdx.x; i < 2 * 2 * 12 * 64 * 8; i += 256) {
        int j = i & 7;
        int r = i >> 3;
        int ln = r & 63;
        int r2 = r >> 6;
        int ct = r2 % 12;
        int r3 = r2 / 12;
        int kt = r3 & 1;
        int mat = r3 >> 1;
        int k = kt * 32 + ((ln >> 4) << 3) + j;
        int n = ct * 16 + (ln & 15);
        float v = mat == 0 ? Wih_g[k * 192 + n] : Whh_g[k * 192 + n];
        Wpk[i] = f2b(v);
    }
    __syncthreads();

    int wid = threadIdx.x >> 6, lane = threadIdx.x & 63;
    int quad = lane >> 4, l16 = lane & 15;

    float bi[3][4], bh[3][4], wv[4][3];
    for (int g = 0; g < 3; ++g)
        for (int cc = 0; cc < 4; ++cc) {
            bi[g][cc] = bih_g[g * 64 + cc * 16 + l16];
            bh[g][cc] = bhh_g[g * 64 + cc * 16 + l16];
        }
    for (int cc = 0; cc < 4; ++cc)
        for (int c = 0; c < 3; ++c)
            wv[cc][c] = Wro_g[(cc * 16 + l16) * 64 + c];
    float bro0 = bro_g[0], bro1 = bro_g[1], bro2 = bro_g[2];

    int wave = blockIdx.x * 4 + wid;
    int n_waves = gridDim.x * 4;
    const f32x4 zero = {0.f, 0.f, 0.f, 0.f};

    for (int tile = wave; tile < GRU_TILES; tile += n_waves) {
        int row0 = tile * 16;
        const bf16* ha_p = hbuf16 + (size_t)(row0 + l16) * 64 + quad * 8;
        bf16x8 ha0 = *(const bf16x8*)ha_p;
        bf16x8 ha1 = *(const bf16x8*)(ha_p + 32);
        const float* pp = h_prev + (size_t)(row0 + l16) * 64 + quad * 8;
        bf16x8 pa0 = pack8(*(const float4*)pp, *(const float4*)(pp + 4));
        bf16x8 pa1 = pack8(*(const float4*)(pp + 32), *(const float4*)(pp + 36));

        float p[4][3];
#pragma unroll
        for (int rg = 0; rg < 4; ++rg) p[rg][0] = p[rg][1] = p[rg][2] = 0.f;

#pragma unroll
        for (int cc = 0; cc < 4; ++cc) {
#define LDB(mat, kt, ct) (*(const bf16x8*)&Wpk[((((mat)*2 + (kt)) * 12 + (ct)) * 64 + lane) * 8])
            f32x4 gir = __builtin_amdgcn_mfma_f32_16x16x32_bf16(ha0, LDB(0, 0, cc), zero, 0, 0, 0);
            gir = __builtin_amdgcn_mfma_f32_16x16x32_bf16(ha1, LDB(0, 1, cc), gir, 0, 0, 0);
            f32x4 giz = __builtin_amdgcn_mfma_f32_16x16x32_bf16(ha0, LDB(0, 0, cc + 4), zero, 0, 0, 0);
            giz = __builtin_amdgcn_mfma_f32_16x16x32_bf16(ha1, LDB(0, 1, cc + 4), giz, 0, 0, 0);
            f32x4 gin = __builtin_amdgcn_mfma_f32_16x16x32_bf16(ha0, LDB(0, 0, cc + 8), zero, 0, 0, 0);
            gin = __builtin_amdgcn_mfma_f32_16x16x32_bf16(ha1, LDB(0, 1, cc + 8), gin, 0, 0, 0);
            f32x4 ghr = __builtin_amdgcn_mfma_f32_16x16x32_bf16(pa0, LDB(1, 0, cc), zero, 0, 0, 0);
            ghr = __builtin_amdgcn_mfma_f32_16x16x32_bf16(pa1, LDB(1, 1, cc), ghr, 0, 0, 0);
            f32x4 ghz = __builtin_amdgcn_mfma_f32_16x16x32_bf16(pa0, LDB(1, 0, cc + 4), zero, 0, 0, 0);
            ghz = __builtin_amdgcn_mfma_f32_16x16x32_bf16(pa1, LDB(1, 1, cc + 4), ghz, 0, 0, 0);
            f32x4 ghn = __builtin_amdgcn_mfma_f32_16x16x32_bf16(pa0, LDB(1, 0, cc + 8), zero, 0, 0, 0);
            ghn = __builtin_amdgcn_mfma_f32_16x16x32_bf16(pa1, LDB(1, 1, cc + 8), ghn, 0, 0, 0);
#undef LDB
#pragma unroll
            for (int rg = 0; rg < 4; ++rg) {
                int row = row0 + quad * 4 + rg;
                float pv = h_prev[(size_t)row * 64 + cc * 16 + l16];
                float rr = 1.f / (1.f + __expf(-(gir[rg] + bi[0][cc] + ghr[rg] + bh[0][cc])));
                float zz = 1.f / (1.f + __expf(-(giz[rg] + bi[1][cc] + ghz[rg] + bh[1][cc])));
                float nn = tanhf(gin[rg] + bi[2][cc] + rr * (ghn[rg] + bh[2][cc]));
                float hn = (1.f - zz) * nn + zz * pv;
                out_h[(size_t)row * 64 + cc * 16 + l16] = hn;
                p[rg][0] += hn * wv[cc][0];
                p[rg][1] += hn * wv[cc][1];
                p[rg][2] += hn * wv[cc][2];
            }
        }
#pragma unroll
        for (int rg = 0; rg < 4; ++rg) {
#pragma unroll
            for (int m = 1; m < 16; m <<= 1) {
                p[rg][0] += __shfl_xor(p[rg][0], m);
                p[rg][1] += __shfl_xor(p[rg][1], m);
                p[rg][2] += __shfl_xor(p[rg][2], m);
            }
        }
        if (l16 == 0) {
#pragma unroll
            for (int rg = 0; rg < 4; ++rg) {
                int row = row0 + quad * 4 + rg;
                out_o[(size_t)row * 3 + 0] = p[rg][0] + bro0;
                out_o[(size_t)row * 3 + 1] = p[rg][1] + bro1;
                out_o[(size_t)row * 3 + 2] = p[rg][2] + bro2;
            }
        }
    }
}

extern "C" void kernel_launch(void* const* d_in, const int* in_sizes, int n_in,
                              void* d_out, int out_size, void* d_ws, size_t ws_size,
                              hipStream_t stream) {
    const float* x        = (const float*)d_in[0];
    const float* h_prev   = (const float*)d_in[1];
    const int* node_idx   = (const int*)d_in[2];
    const int* hedge_idx  = (const int*)d_in[3];
    const int* edge_attr  = (const int*)d_in[4];
    const float* W_conv   = (const float*)d_in[5];
    const float* b_conv   = (const float*)d_in[6];
    const float* W_mix    = (const float*)d_in[7];
    const float* b_mix    = (const float*)d_in[8];
    const float* W_ih     = (const float*)d_in[9];
    const float* W_hh     = (const float*)d_in[10];
    const float* b_ih     = (const float*)d_in[11];
    const float* b_hh     = (const float*)d_in[12];
    const float* W_ro     = (const float*)d_in[13];
    const float* b_ro     = (const float*)d_in[14];

    // Workspace (~80 MB): counters/offsets | sorted edge lists | bf16 tensors
    char* p = (char*)d_ws;
    auto alloc = [&](size_t bytes) {
        char* r = p;
        p += (bytes + 63) & ~(size_t)63;
        return r;
    };
    int* cnt       = (int*)alloc((size_t)MSEG * 4);        // [zeroed]
    int* off       = (int*)alloc((size_t)(MSEG + 1) * 4);
    int* cursor    = (int*)alloc((size_t)MSEG * 4);
    int* bsum      = (int*)alloc(1024 * 4);
    int* sortedAll = (int*)alloc((size_t)2 * N_EDGES * 4);
    bf16* xl       = (bf16*)alloc((size_t)2 * N_NODES * 64 * 2);
    bf16* ef16     = (bf16*)alloc((size_t)HSEG * 64 * 2);
    bf16* mixin16  = (bf16*)alloc((size_t)NSEG * 64 * 2);
    bf16* hbuf16   = (bf16*)alloc((size_t)N_NODES * 64 * 2);

    hipMemsetAsync(cnt, 0, (size_t)MSEG * 4, stream);

    float* out_h = (float*)d_out;
    float* out_o = out_h + (size_t)N_NODES * 64;

    k_conv<<<512, 256, 0, stream>>>(x, W_conv, xl);
    k_hist<<<(N_EDGES + 255) / 256, 256, 0, stream>>>(node_idx, hedge_idx, edge_attr, cnt);
    k_scan1<<<SCAN_BLOCKS, 256, 0, stream>>>(cnt, off, bsum);
    k_scan2<<<1, 1024, 0, stream>>>(bsum);
    k_scan3<<<SCAN_BLOCKS, 256, 0, stream>>>(off, bsum, cursor);
    k_scatter<<<(N_EDGES + 255) / 256, 256, 0, stream>>>(node_idx, hedge_idx, edge_attr,
                                                         cursor, sortedAll);
    k_ef2<<<(HSEG + 3) / 4, 256, 0, stream>>>(off, sortedAll, xl, ef16);
    k_no2<<<(NSEG + 3) / 4, 256, 0, stream>>>(off, sortedAll, ef16, b_conv, mixin16);
    k_mix<<<512, 256, 0, stream>>>(mixin16, W_mix, b_mix, hbuf16);
    k_gru<<<512, 256, 0, stream>>>(hbuf16, h_prev, W_ih, W_hh, b_ih, b_hh,
                                   W_ro, b_ro, out_h, out_o);
}